// Round 3
// baseline (5500.792 us; speedup 1.0000x reference)
//
#include <hip/hip_runtime.h>

#define USER_NUM 100000
#define ITEM_NUM 150000
#define NTOT     250000           // USER_NUM + ITEM_NUM
#define EMB      64
#define NNZ      5000000
#define NROW_ELEMS (NTOT * EMB)   // 16,000,000 floats = 64 MB
#define NB       3907             // ceil(NTOT/64) buckets of 64 rows
#define LPAD     68               // LDS row pitch (floats), pad to spread banks

// ============================ bucket-CSR build ===============================

// per-block LDS histogram of 64-row buckets, flushed with global atomics
__global__ void hist_kernel(const int* __restrict__ rows, int* __restrict__ counts) {
    __shared__ int sh[NB];
    for (int i = threadIdx.x; i < NB; i += blockDim.x) sh[i] = 0;
    __syncthreads();
    int stride = gridDim.x * blockDim.x;
    for (int e = blockIdx.x * blockDim.x + threadIdx.x; e < NNZ; e += stride)
        atomicAdd(&sh[rows[e] >> 6], 1);
    __syncthreads();
    for (int i = threadIdx.x; i < NB; i += blockDim.x)
        if (sh[i]) atomicAdd(&counts[i], sh[i]);
}

// single-block exclusive scan over NB=3907 counts -> offs + cursor; offs[NB]=NNZ
__global__ void scan_kernel(const int* __restrict__ counts, int* __restrict__ offs,
                            int* __restrict__ cursor) {
    __shared__ int sm[1024];
    int t = threadIdx.x;
    int c[4]; int T = 0;
#pragma unroll
    for (int k = 0; k < 4; ++k) {
        int idx = t * 4 + k;
        c[k] = (idx < NB) ? counts[idx] : 0;
        T += c[k];
    }
    sm[t] = T; __syncthreads();
    for (int off = 1; off < 1024; off <<= 1) {
        int v = (t >= off) ? sm[t - off] : 0;
        __syncthreads();
        sm[t] += v;
        __syncthreads();
    }
    int run = sm[t] - T;   // exclusive base for this thread's 4 buckets
#pragma unroll
    for (int k = 0; k < 4; ++k) {
        int idx = t * 4 + k;
        if (idx < NB) { offs[idx] = run; cursor[idx] = run; run += c[k]; }
    }
    if (t == 1023) offs[NB] = sm[1023];
}

// bin edges by bucket; pack (col | localrow<<24, val). col<2^18, lrow<2^6.
__global__ void scatter_kernel(const int* __restrict__ rows, const int* __restrict__ cols,
                               const float* __restrict__ vals, int* __restrict__ cursor,
                               int2* __restrict__ epk) {
    int e = blockIdx.x * blockDim.x + threadIdx.x;
    if (e >= NNZ) return;
    int r = rows[e];
    int b = r >> 6;
    unsigned ex = (unsigned)cols[e] | ((unsigned)(r & 63) << 24);
    int p = atomicAdd(&cursor[b], 1);
    epk[p] = make_int2((int)ex, __float_as_int(vals[e]));
}

// ==================== bucket SpMM with LDS accumulation ======================
// One block per bucket. LDS tile: 64 rows x 64 dims (pitch LPAD).
// Accumulate: wave w handles 8 edges/iter, lane = dim, ds_add_f32.
// LAYER 1: x = concat(ue,ie); lout=ws0; out = ego0 + l
// LAYER 2: x = xu;            lout=outCL; out += l
// LAYER 3: x = xu;            out = (out + l) * 0.25

template <int LAYER>
__global__ __launch_bounds__(256) void spmm_bucket(
        const float* __restrict__ xu, const float* __restrict__ xi,
        const int* __restrict__ offs, const int2* __restrict__ epk,
        float* __restrict__ lout, float* __restrict__ out) {
    __shared__ float lds[64 * LPAD];
    int b = blockIdx.x;
    int t = threadIdx.x;
    for (int i = t; i < 64 * LPAD; i += 256) lds[i] = 0.f;
    __syncthreads();

    int beg = offs[b], end = offs[b + 1];
    int lane = t & 63;
    int w = t >> 6;                    // wave 0..3
    for (int j = beg + w * 8; j < end; j += 32) {
#pragma unroll
        for (int k = 0; k < 8; ++k) {
            int jj = j + k;
            if (jj < end) {
                int2 e = epk[jj];
                unsigned ex = (unsigned)e.x;
                int col = (int)(ex & 0xFFFFFFu << 0) & 0xFFFFFF;
                int lr  = (int)(ex >> 24);
                float v = __int_as_float(e.y);
                float x;
                if (LAYER == 1)
                    x = (col < USER_NUM) ? xu[col * EMB + lane]
                                         : xi[(col - USER_NUM) * EMB + lane];
                else
                    x = xu[col * EMB + lane];
                unsafeAtomicAdd(&lds[lr * LPAD + lane], v * x);
            }
        }
    }
    __syncthreads();

    // write-out: thread t -> local row t>>2, dim quarter t&3 (16 floats)
    int lr = t >> 2, q = t & 3;
    int r = b * 64 + lr;
    if (r >= NTOT) return;
    const float4* ue4 = (const float4*)xu;   // LAYER 1 only
    const float4* ie4 = (const float4*)xi;
#pragma unroll
    for (int k = 0; k < 4; ++k) {
        float4 v = *(const float4*)&lds[lr * LPAD + q * 16 + k * 4];
        int idx = r * 16 + q * 4 + k;        // float4 index
        if (LAYER == 1) {
            ((float4*)lout)[idx] = v;
            float4 e0 = (r < USER_NUM) ? ue4[idx] : ie4[(r - USER_NUM) * 16 + q * 4 + k];
            v.x += e0.x; v.y += e0.y; v.z += e0.z; v.w += e0.w;
            ((float4*)out)[idx] = v;
        } else if (LAYER == 2) {
            ((float4*)lout)[idx] = v;
            float4 a = ((const float4*)out)[idx];
            a.x += v.x; a.y += v.y; a.z += v.z; a.w += v.w;
            ((float4*)out)[idx] = a;
        } else {
            float4 a = ((const float4*)out)[idx];
            a.x = (a.x + v.x) * 0.25f; a.y = (a.y + v.y) * 0.25f;
            a.z = (a.z + v.z) * 0.25f; a.w = (a.w + v.w) * 0.25f;
            ((float4*)out)[idx] = a;
        }
    }
}

// ===================== pass-throughs (written LAST: cl region) ===============
__global__ void copy_pass(const float* __restrict__ ue,
                          const float* __restrict__ ie,
                          const float* __restrict__ up,
                          const float* __restrict__ ip,
                          float* __restrict__ out) {
    const int CL4 = NROW_ELEMS / 4;
    const int U4  = USER_NUM * EMB / 4;
    const int P4  = 2048 * 64 / 4;
    int i = blockIdx.x * blockDim.x + threadIdx.x;
    if (i < CL4) {
        float4 v = (i < U4) ? ((const float4*)ue)[i]
                            : ((const float4*)ie)[i - U4];
        ((float4*)(out + NROW_ELEMS))[i] = v;
    } else {
        int j = i - CL4;
        if (j < P4) {
            ((float4*)(out + 2 * NROW_ELEMS))[j] = ((const float4*)up)[j];
        } else if (j < 2 * P4) {
            ((float4*)(out + 2 * NROW_ELEMS + 2048 * 64))[j - P4] =
                ((const float4*)ip)[j - P4];
        }
    }
}

// =============================================================================
extern "C" void kernel_launch(void* const* d_in, const int* in_sizes, int n_in,
                              void* d_out, int out_size, void* d_ws, size_t ws_size,
                              hipStream_t stream) {
    const float* ue   = (const float*)d_in[0];
    const float* ie   = (const float*)d_in[1];
    const float* up   = (const float*)d_in[2];
    const float* ip   = (const float*)d_in[3];
    const float* vals = (const float*)d_in[4];
    const int*   rows = (const int*)d_in[5];
    const int*   cols = (const int*)d_in[6];
    float* out = (float*)d_out;

    // ws layout (4-byte units):
    //   [0, 16M)            ws0    : layer-1 buffer (64 MB)
    //   [16M, 26M)          epk    : 5M int2 bucket-sorted edges (40 MB)
    //   [26,000,000 ...]    offs   : NB+1
    //   [26,004,000 ...]    cursor : NB
    //   [26,008,000 ...]    counts : NB
    float* ws0   = (float*)d_ws;
    int2*  epk   = (int2*)((int*)d_ws + 16000000);
    int*   offs  = (int*)d_ws + 26000000;
    int*   cursor= (int*)d_ws + 26004000;
    int*   counts= (int*)d_ws + 26008000;

    // layer-2 output lives in the user_cl/item_cl region of d_out, rewritten
    // with ego0 by copy_pass at the very end.
    float* outCL = out + NROW_ELEMS;

    const int egrid = (NNZ + 255) / 256;             // 19,532

    // ---- build bucket-sorted edge list ----
    hipMemsetAsync(counts, 0, NB * sizeof(int), stream);
    hist_kernel   <<<256, 256, 0, stream>>>(rows, counts);
    scan_kernel   <<<1, 1024, 0, stream>>>(counts, offs, cursor);
    scatter_kernel<<<egrid, 256, 0, stream>>>(rows, cols, vals, cursor, epk);

    // ---- 3 bucket-SpMM layers with fused accumulation ----
    spmm_bucket<1><<<NB, 256, 0, stream>>>(ue, ie, offs, epk, ws0, out);
    spmm_bucket<2><<<NB, 256, 0, stream>>>(ws0, nullptr, offs, epk, outCL, out);
    spmm_bucket<3><<<NB, 256, 0, stream>>>(outCL, nullptr, offs, epk, nullptr, out);

    // ---- pass-through copies last (restores cl region + protos) ----
    {
        int total4 = NROW_ELEMS / 4 + 2 * (2048 * 64 / 4);
        int grid = (total4 + 255) / 256;
        copy_pass<<<grid, 256, 0, stream>>>(ue, ie, up, ip, out);
    }
}

// Round 4
// 1037.365 us; speedup vs baseline: 5.3027x; 5.3027x over previous
//
#include <hip/hip_runtime.h>

#define USER_NUM 100000
#define ITEM_NUM 150000
#define NTOT     250000           // USER_NUM + ITEM_NUM
#define EMB      64
#define NNZ      5000000
#define NROW_ELEMS (NTOT * EMB)   // 16,000,000 floats = 64 MB
#define NB       3907             // ceil(NTOT/64) buckets of 64 rows
#define SCAP     3072             // per-bucket LDS edge capacity (mean 1280, +50 sigma)

// ============================ bucket-CSR build ===============================

// per-block LDS histogram of 64-row buckets, flushed with global atomics
__global__ void hist_kernel(const int* __restrict__ rows, int* __restrict__ counts) {
    __shared__ int sh[NB];
    for (int i = threadIdx.x; i < NB; i += blockDim.x) sh[i] = 0;
    __syncthreads();
    int stride = gridDim.x * blockDim.x;
    for (int e = blockIdx.x * blockDim.x + threadIdx.x; e < NNZ; e += stride)
        atomicAdd(&sh[rows[e] >> 6], 1);
    __syncthreads();
    for (int i = threadIdx.x; i < NB; i += blockDim.x)
        if (sh[i]) atomicAdd(&counts[i], sh[i]);
}

// single-block exclusive scan over NB=3907 counts -> boffs + bcursor
__global__ void scan_kernel(const int* __restrict__ counts, int* __restrict__ boffs,
                            int* __restrict__ bcursor) {
    __shared__ int sm[1024];
    int t = threadIdx.x;
    int c[4]; int T = 0;
#pragma unroll
    for (int k = 0; k < 4; ++k) {
        int idx = t * 4 + k;
        c[k] = (idx < NB) ? counts[idx] : 0;
        T += c[k];
    }
    sm[t] = T; __syncthreads();
    for (int off = 1; off < 1024; off <<= 1) {
        int v = (t >= off) ? sm[t - off] : 0;
        __syncthreads();
        sm[t] += v;
        __syncthreads();
    }
    int run = sm[t] - T;   // exclusive base for this thread's 4 buckets
#pragma unroll
    for (int k = 0; k < 4; ++k) {
        int idx = t * 4 + k;
        if (idx < NB) { boffs[idx] = run; bcursor[idx] = run; run += c[k]; }
    }
    if (t == 1023) boffs[NB] = sm[1023];
}

// bin edges by 64-row bucket; pack (localrow<<24 | col, val). col<2^18, lr<2^6.
__global__ void scatter_kernel(const int* __restrict__ rows, const int* __restrict__ cols,
                               const float* __restrict__ vals, int* __restrict__ bcursor,
                               int2* __restrict__ epk) {
    int e = blockIdx.x * blockDim.x + threadIdx.x;
    if (e >= NNZ) return;
    int r = rows[e];
    int b = r >> 6;
    unsigned ex = (unsigned)cols[e] | ((unsigned)(r & 63) << 24);
    int p = atomicAdd(&bcursor[b], 1);
    epk[p] = make_int2((int)ex, __float_as_int(vals[e]));
}

// per-bucket in-LDS row sort: bucket-grouped edges -> fully row-sorted, in place.
// Also emits per-row CSR offsets. Strips the localrow tag from the packed word.
__global__ __launch_bounds__(256) void bucket_sort(const int* __restrict__ boffs,
                                                   int2* __restrict__ epk,
                                                   int* __restrict__ offs) {
    __shared__ int2 se[SCAP];
    __shared__ int cnt[64];
    __shared__ int base[64];
    int b = blockIdx.x, t = threadIdx.x;
    int beg = boffs[b], end = boffs[b + 1];
    int n = end - beg;
    if (n > SCAP) n = SCAP;   // statistically impossible (mean 1280, +50 sigma)
    if (t < 64) cnt[t] = 0;
    __syncthreads();
    // stage bucket in LDS + count per local row
    for (int i = t; i < n; i += 256) {
        int2 e = epk[beg + i];
        se[i] = e;
        atomicAdd(&cnt[((unsigned)e.x) >> 24], 1);
    }
    __syncthreads();
    if (t == 0) {
        int run = beg;
#pragma unroll
        for (int i = 0; i < 64; ++i) { base[i] = run; run += cnt[i]; }
    }
    __syncthreads();
    if (t < 64) {
        offs[b * 64 + t] = base[t];   // global row offsets (rows >= NTOT get end)
        cnt[t] = 0;                   // reuse as local cursor
    }
    __syncthreads();
    // scatter back to the same global range, row-sorted
    for (int i = t; i < n; i += 256) {
        int2 e = se[i];
        int lr = (int)(((unsigned)e.x) >> 24);
        int p = base[lr] + atomicAdd(&cnt[lr], 1);
        epk[p] = make_int2((int)(((unsigned)e.x) & 0xFFFFFFu), e.y);
    }
}

// ============================ CSR SpMM (no atomics) ==========================
// 16 lanes per row; lane l owns dims [4l, 4l+4) as float4; register accumulate.

__device__ __forceinline__ void fmaf4(float4& a, float v, float4 x) {
    a.x += v * x.x; a.y += v * x.y; a.z += v * x.z; a.w += v * x.w;
}

// LAYER 1: x = concat(ue,ie); lout=ws0; out = ego0 + l
// LAYER 2: x = xu;            lout=outCL; out += l
// LAYER 3: x = xu;            out = (out + l) * 0.25   (l never stored)
template <int LAYER>
__global__ __launch_bounds__(256) void spmm_row(
        const float* __restrict__ xu, const float* __restrict__ xi,
        const int* __restrict__ offs, const int2* __restrict__ epk,
        float* __restrict__ lout, float* __restrict__ out) {
    int t = blockIdx.x * blockDim.x + threadIdx.x;
    int r = t >> 4, l = t & 15;
    if (r >= NTOT) return;
    const float4* xu4 = (const float4*)xu;
    const float4* xi4 = (const float4*)xi;
    int beg = offs[r], end = offs[r + 1];
    float4 acc = make_float4(0.f, 0.f, 0.f, 0.f);
    int j = beg;
    for (; j + 3 < end; j += 4) {
        int2 e0 = epk[j], e1 = epk[j + 1], e2 = epk[j + 2], e3 = epk[j + 3];
        float4 x0, x1, x2, x3;
        if (LAYER == 1) {
            x0 = (e0.x < USER_NUM) ? xu4[e0.x * 16 + l] : xi4[(e0.x - USER_NUM) * 16 + l];
            x1 = (e1.x < USER_NUM) ? xu4[e1.x * 16 + l] : xi4[(e1.x - USER_NUM) * 16 + l];
            x2 = (e2.x < USER_NUM) ? xu4[e2.x * 16 + l] : xi4[(e2.x - USER_NUM) * 16 + l];
            x3 = (e3.x < USER_NUM) ? xu4[e3.x * 16 + l] : xi4[(e3.x - USER_NUM) * 16 + l];
        } else {
            x0 = xu4[e0.x * 16 + l]; x1 = xu4[e1.x * 16 + l];
            x2 = xu4[e2.x * 16 + l]; x3 = xu4[e3.x * 16 + l];
        }
        fmaf4(acc, __int_as_float(e0.y), x0);
        fmaf4(acc, __int_as_float(e1.y), x1);
        fmaf4(acc, __int_as_float(e2.y), x2);
        fmaf4(acc, __int_as_float(e3.y), x3);
    }
    for (; j < end; ++j) {
        int2 e0 = epk[j];
        float4 x0;
        if (LAYER == 1)
            x0 = (e0.x < USER_NUM) ? xu4[e0.x * 16 + l] : xi4[(e0.x - USER_NUM) * 16 + l];
        else
            x0 = xu4[e0.x * 16 + l];
        fmaf4(acc, __int_as_float(e0.y), x0);
    }
    int idx = r * 16 + l;
    if (LAYER == 1) {
        ((float4*)lout)[idx] = acc;
        float4 e0r = (r < USER_NUM) ? xu4[idx] : xi4[(r - USER_NUM) * 16 + l];
        acc.x += e0r.x; acc.y += e0r.y; acc.z += e0r.z; acc.w += e0r.w;
        ((float4*)out)[idx] = acc;
    } else if (LAYER == 2) {
        ((float4*)lout)[idx] = acc;
        float4 a = ((const float4*)out)[idx];
        a.x += acc.x; a.y += acc.y; a.z += acc.z; a.w += acc.w;
        ((float4*)out)[idx] = a;
    } else {
        float4 a = ((const float4*)out)[idx];
        a.x = (a.x + acc.x) * 0.25f; a.y = (a.y + acc.y) * 0.25f;
        a.z = (a.z + acc.z) * 0.25f; a.w = (a.w + acc.w) * 0.25f;
        ((float4*)out)[idx] = a;
    }
}

// ===================== pass-throughs (written LAST: cl region) ===============
__global__ void copy_pass(const float* __restrict__ ue,
                          const float* __restrict__ ie,
                          const float* __restrict__ up,
                          const float* __restrict__ ip,
                          float* __restrict__ out) {
    const int CL4 = NROW_ELEMS / 4;
    const int U4  = USER_NUM * EMB / 4;
    const int P4  = 2048 * 64 / 4;
    int i = blockIdx.x * blockDim.x + threadIdx.x;
    if (i < CL4) {
        float4 v = (i < U4) ? ((const float4*)ue)[i]
                            : ((const float4*)ie)[i - U4];
        ((float4*)(out + NROW_ELEMS))[i] = v;
    } else {
        int j = i - CL4;
        if (j < P4) {
            ((float4*)(out + 2 * NROW_ELEMS))[j] = ((const float4*)up)[j];
        } else if (j < 2 * P4) {
            ((float4*)(out + 2 * NROW_ELEMS + 2048 * 64))[j - P4] =
                ((const float4*)ip)[j - P4];
        }
    }
}

// =============================================================================
extern "C" void kernel_launch(void* const* d_in, const int* in_sizes, int n_in,
                              void* d_out, int out_size, void* d_ws, size_t ws_size,
                              hipStream_t stream) {
    const float* ue   = (const float*)d_in[0];
    const float* ie   = (const float*)d_in[1];
    const float* up   = (const float*)d_in[2];
    const float* ip   = (const float*)d_in[3];
    const float* vals = (const float*)d_in[4];
    const int*   rows = (const int*)d_in[5];
    const int*   cols = (const int*)d_in[6];
    float* out = (float*)d_out;

    // ws layout (4-byte units):
    //   [0, 16M)            ws0     : layer-1 buffer (64 MB)
    //   [16M, 26M)          epk     : 5M int2 edges, bucket- then row-sorted (40 MB)
    //   26,000,000          offs    : NB*64+1 row offsets (250,049)
    //   26,250,112          boffs   : NB+1
    //   26,254,080          bcursor : NB
    //   26,258,048          bcounts : NB
    float* ws0    = (float*)d_ws;
    int2*  epk    = (int2*)((int*)d_ws + 16000000);
    int*   offs   = (int*)d_ws + 26000000;
    int*   boffs  = (int*)d_ws + 26250112;
    int*   bcursor= (int*)d_ws + 26254080;
    int*   bcounts= (int*)d_ws + 26258048;

    // layer-2 output lives in the user_cl/item_cl region of d_out, rewritten
    // with ego0 by copy_pass at the very end.
    float* outCL = out + NROW_ELEMS;

    const int egrid = (NNZ + 255) / 256;             // 19,532
    const int rgrid = (NTOT * 16 + 255) / 256;       // 15,625

    // ---- build row-sorted CSR (bucket scatter + in-LDS per-bucket sort) ----
    hipMemsetAsync(bcounts, 0, NB * sizeof(int), stream);
    hist_kernel   <<<256, 256, 0, stream>>>(rows, bcounts);
    scan_kernel   <<<1, 1024, 0, stream>>>(bcounts, boffs, bcursor);
    scatter_kernel<<<egrid, 256, 0, stream>>>(rows, cols, vals, bcursor, epk);
    bucket_sort   <<<NB, 256, 0, stream>>>(boffs, epk, offs);

    // ---- 3 CSR SpMM layers with fused accumulation ----
    spmm_row<1><<<rgrid, 256, 0, stream>>>(ue, ie, offs, epk, ws0, out);
    spmm_row<2><<<rgrid, 256, 0, stream>>>(ws0, nullptr, offs, epk, outCL, out);
    spmm_row<3><<<rgrid, 256, 0, stream>>>(outCL, nullptr, offs, epk, nullptr, out);

    // ---- pass-through copies last (restores cl region + protos) ----
    {
        int total4 = NROW_ELEMS / 4 + 2 * (2048 * 64 / 4);
        int grid = (total4 + 255) / 256;
        copy_pass<<<grid, 256, 0, stream>>>(ue, ie, up, ip, out);
    }
}

// Round 5
// 812.687 us; speedup vs baseline: 6.7686x; 1.2765x over previous
//
#include <hip/hip_runtime.h>

#define USER_NUM 100000
#define ITEM_NUM 150000
#define NTOT     250000           // USER_NUM + ITEM_NUM
#define EMB      64
#define NNZ      5000000
#define NROW_ELEMS (NTOT * EMB)   // 16,000,000 floats = 64 MB
#define NCB      977              // ceil(NTOT/256) coarse buckets of 256 rows
#define TILE     8192             // edges per scatter block
#define NTILES   ((NNZ + TILE - 1) / TILE)     // 611
#define SCAP     6144             // per-coarse-bucket LDS cap (mean 5120, +14 sigma)

// ============================ coarse histogram ===============================
// LDS histogram of 977 coarse buckets per block, flushed with global atomics.
__global__ __launch_bounds__(256) void hist_kernel(const int* __restrict__ rows,
                                                   int* __restrict__ counts) {
    __shared__ int sh[NCB];
    for (int i = threadIdx.x; i < NCB; i += 256) sh[i] = 0;
    __syncthreads();
    int stride = gridDim.x * blockDim.x;
    const int4* rows4 = (const int4*)rows;
    for (int i = blockIdx.x * blockDim.x + threadIdx.x; i < NNZ / 4; i += stride) {
        int4 r = rows4[i];
        atomicAdd(&sh[r.x >> 8], 1);
        atomicAdd(&sh[r.y >> 8], 1);
        atomicAdd(&sh[r.z >> 8], 1);
        atomicAdd(&sh[r.w >> 8], 1);
    }
    __syncthreads();
    for (int i = threadIdx.x; i < NCB; i += 256)
        if (sh[i]) atomicAdd(&counts[i], sh[i]);
}

// exclusive scan over NCB<=1024 counts -> boffs + bcursor; also offs[NTOT]=NNZ
__global__ void scan_kernel(const int* __restrict__ counts, int* __restrict__ boffs,
                            int* __restrict__ bcursor, int* __restrict__ offs) {
    __shared__ int sm[1024];
    int t = threadIdx.x;
    int c = (t < NCB) ? counts[t] : 0;
    sm[t] = c; __syncthreads();
    for (int off = 1; off < 1024; off <<= 1) {
        int v = (t >= off) ? sm[t - off] : 0;
        __syncthreads();
        sm[t] += v;
        __syncthreads();
    }
    if (t < NCB) { boffs[t] = sm[t] - c; bcursor[t] = sm[t] - c; }
    if (t == 1023) { boffs[NCB] = sm[1023]; offs[NTOT] = sm[1023]; }
}

// ================= tile scatter with in-block write combining ================
// Each block owns TILE consecutive edges: LDS-rank them per coarse bucket,
// claim one contiguous global run per (tile,bucket), write runs from THIS
// block only -> epk lines assemble inside a single XCD's L2.
// Packed word: col (bits 0..17) | localrow-in-256 (bits 18..25).
__global__ __launch_bounds__(256) void scatter_tile(
        const int* __restrict__ rows, const int* __restrict__ cols,
        const float* __restrict__ vals, int* __restrict__ bcursor,
        int2* __restrict__ epk) {
    __shared__ unsigned meta[TILE];   // cb<<22 | lr<<13 | rank   (32 KB)
    __shared__ int cnt[NCB];
    __shared__ int base[NCB];
    int t = threadIdx.x;
    int tb = blockIdx.x * TILE;
    int nmax = NNZ - tb; if (nmax > TILE) nmax = TILE;
    for (int i = t; i < NCB; i += 256) cnt[i] = 0;
    __syncthreads();
    for (int i = t; i < nmax; i += 256) {
        int r = rows[tb + i];
        int cb = r >> 8;
        int rank = atomicAdd(&cnt[cb], 1);
        meta[i] = ((unsigned)cb << 22) | ((unsigned)(r & 255) << 13) | (unsigned)rank;
    }
    __syncthreads();
    for (int i = t; i < NCB; i += 256) {
        int c = cnt[i];
        if (c) base[i] = atomicAdd(&bcursor[i], c);
    }
    __syncthreads();
    for (int i = t; i < nmax; i += 256) {
        unsigned m = meta[i];
        int cb = (int)(m >> 22);
        int lr = (int)((m >> 13) & 0x1FFu);
        int rank = (int)(m & 0x1FFFu);
        unsigned ex = (unsigned)cols[tb + i] | ((unsigned)lr << 18);
        epk[base[cb] + rank] = make_int2((int)ex, __float_as_int(vals[tb + i]));
    }
}

// ============== per-coarse-bucket in-LDS row sort + CSR offsets ==============
// One block per 256-row bucket (~5.1K edges). Stage whole range in LDS, count
// per row, scan, scatter back to the SAME range row-sorted (all writes from
// this block -> perfect combining). Strips the localrow tag.
__global__ __launch_bounds__(256) void bucket_sort(const int* __restrict__ boffs,
                                                   int2* __restrict__ epk,
                                                   int* __restrict__ offs) {
    __shared__ int2 se[SCAP];         // 48 KB
    __shared__ int cnt[256];
    __shared__ int base[256];
    __shared__ int cur[256];
    int b = blockIdx.x, t = threadIdx.x;
    int beg = boffs[b], end = boffs[b + 1];
    int n = end - beg; if (n > SCAP) n = SCAP;   // +14 sigma, unreachable
    cnt[t] = 0;
    __syncthreads();
    for (int i = t; i < n; i += 256) {
        int2 e = epk[beg + i];
        se[i] = e;
        atomicAdd(&cnt[(((unsigned)e.x) >> 18) & 0xFFu], 1);
    }
    __syncthreads();
    int c = cnt[t];
    base[t] = c; __syncthreads();
    for (int off = 1; off < 256; off <<= 1) {     // Hillis-Steele inclusive
        int v = (t >= off) ? base[t - off] : 0;
        __syncthreads();
        base[t] += v;
        __syncthreads();
    }
    int mybase = beg + base[t] - c;               // exclusive + global base
    cur[t] = mybase;
    int r = b * 256 + t;
    if (r < NTOT) offs[r] = mybase;
    __syncthreads();
    for (int i = t; i < n; i += 256) {
        int2 e = se[i];
        int lr = (int)((((unsigned)e.x) >> 18) & 0xFFu);
        int p = atomicAdd(&cur[lr], 1);
        epk[p] = make_int2((int)(((unsigned)e.x) & 0x3FFFFu), e.y);
    }
}

// ============================ CSR SpMM (no atomics) ==========================
// 16 lanes per row; lane l owns dims [4l, 4l+4) as float4; register accumulate.

__device__ __forceinline__ void fmaf4(float4& a, float v, float4 x) {
    a.x += v * x.x; a.y += v * x.y; a.z += v * x.z; a.w += v * x.w;
}

// LAYER 1: x = concat(ue,ie); lout=ws0; out = ego0 + l
// LAYER 2: x = xu;            lout=outCL; out += l
// LAYER 3: x = xu;            out = (out + l) * 0.25   (l never stored)
template <int LAYER>
__global__ __launch_bounds__(256) void spmm_row(
        const float* __restrict__ xu, const float* __restrict__ xi,
        const int* __restrict__ offs, const int2* __restrict__ epk,
        float* __restrict__ lout, float* __restrict__ out) {
    int t = blockIdx.x * blockDim.x + threadIdx.x;
    int r = t >> 4, l = t & 15;
    if (r >= NTOT) return;
    const float4* xu4 = (const float4*)xu;
    const float4* xi4 = (const float4*)xi;
    int beg = offs[r], end = offs[r + 1];
    float4 acc = make_float4(0.f, 0.f, 0.f, 0.f);
    int j = beg;
    for (; j + 3 < end; j += 4) {
        int2 e0 = epk[j], e1 = epk[j + 1], e2 = epk[j + 2], e3 = epk[j + 3];
        float4 x0, x1, x2, x3;
        if (LAYER == 1) {
            x0 = (e0.x < USER_NUM) ? xu4[e0.x * 16 + l] : xi4[(e0.x - USER_NUM) * 16 + l];
            x1 = (e1.x < USER_NUM) ? xu4[e1.x * 16 + l] : xi4[(e1.x - USER_NUM) * 16 + l];
            x2 = (e2.x < USER_NUM) ? xu4[e2.x * 16 + l] : xi4[(e2.x - USER_NUM) * 16 + l];
            x3 = (e3.x < USER_NUM) ? xu4[e3.x * 16 + l] : xi4[(e3.x - USER_NUM) * 16 + l];
        } else {
            x0 = xu4[e0.x * 16 + l]; x1 = xu4[e1.x * 16 + l];
            x2 = xu4[e2.x * 16 + l]; x3 = xu4[e3.x * 16 + l];
        }
        fmaf4(acc, __int_as_float(e0.y), x0);
        fmaf4(acc, __int_as_float(e1.y), x1);
        fmaf4(acc, __int_as_float(e2.y), x2);
        fmaf4(acc, __int_as_float(e3.y), x3);
    }
    for (; j < end; ++j) {
        int2 e0 = epk[j];
        float4 x0;
        if (LAYER == 1)
            x0 = (e0.x < USER_NUM) ? xu4[e0.x * 16 + l] : xi4[(e0.x - USER_NUM) * 16 + l];
        else
            x0 = xu4[e0.x * 16 + l];
        fmaf4(acc, __int_as_float(e0.y), x0);
    }
    int idx = r * 16 + l;
    if (LAYER == 1) {
        ((float4*)lout)[idx] = acc;
        float4 e0r = (r < USER_NUM) ? xu4[idx] : xi4[(r - USER_NUM) * 16 + l];
        acc.x += e0r.x; acc.y += e0r.y; acc.z += e0r.z; acc.w += e0r.w;
        ((float4*)out)[idx] = acc;
    } else if (LAYER == 2) {
        ((float4*)lout)[idx] = acc;
        float4 a = ((const float4*)out)[idx];
        a.x += acc.x; a.y += acc.y; a.z += acc.z; a.w += acc.w;
        ((float4*)out)[idx] = a;
    } else {
        float4 a = ((const float4*)out)[idx];
        a.x = (a.x + acc.x) * 0.25f; a.y = (a.y + acc.y) * 0.25f;
        a.z = (a.z + acc.z) * 0.25f; a.w = (a.w + acc.w) * 0.25f;
        ((float4*)out)[idx] = a;
    }
}

// ===================== pass-throughs (written LAST: cl region) ===============
__global__ void copy_pass(const float* __restrict__ ue,
                          const float* __restrict__ ie,
                          const float* __restrict__ up,
                          const float* __restrict__ ip,
                          float* __restrict__ out) {
    const int CL4 = NROW_ELEMS / 4;
    const int U4  = USER_NUM * EMB / 4;
    const int P4  = 2048 * 64 / 4;
    int i = blockIdx.x * blockDim.x + threadIdx.x;
    if (i < CL4) {
        float4 v = (i < U4) ? ((const float4*)ue)[i]
                            : ((const float4*)ie)[i - U4];
        ((float4*)(out + NROW_ELEMS))[i] = v;
    } else {
        int j = i - CL4;
        if (j < P4) {
            ((float4*)(out + 2 * NROW_ELEMS))[j] = ((const float4*)up)[j];
        } else if (j < 2 * P4) {
            ((float4*)(out + 2 * NROW_ELEMS + 2048 * 64))[j - P4] =
                ((const float4*)ip)[j - P4];
        }
    }
}

// =============================================================================
extern "C" void kernel_launch(void* const* d_in, const int* in_sizes, int n_in,
                              void* d_out, int out_size, void* d_ws, size_t ws_size,
                              hipStream_t stream) {
    const float* ue   = (const float*)d_in[0];
    const float* ie   = (const float*)d_in[1];
    const float* up   = (const float*)d_in[2];
    const float* ip   = (const float*)d_in[3];
    const float* vals = (const float*)d_in[4];
    const int*   rows = (const int*)d_in[5];
    const int*   cols = (const int*)d_in[6];
    float* out = (float*)d_out;

    // ws layout (4-byte units):
    //   [0, 16M)        ws0     : layer-1 buffer (64 MB)
    //   [16M, 26M)      epk     : 5M int2 edges, coarse- then row-sorted (40 MB)
    //   26,000,000      offs    : NTOT+1 row offsets
    //   26,250,112      boffs   : NCB+1
    //   26,252,000      bcursor : NCB
    //   26,253,000      bcounts : NCB
    float* ws0    = (float*)d_ws;
    int2*  epk    = (int2*)((int*)d_ws + 16000000);
    int*   offs   = (int*)d_ws + 26000000;
    int*   boffs  = (int*)d_ws + 26250112;
    int*   bcursor= (int*)d_ws + 26252000;
    int*   bcounts= (int*)d_ws + 26253000;

    // layer-2 output lives in the user_cl/item_cl region of d_out, rewritten
    // with ego0 by copy_pass at the very end.
    float* outCL = out + NROW_ELEMS;

    const int rgrid = (NTOT * 16 + 255) / 256;       // 15,625

    // ---- build row-sorted CSR (tile scatter + per-bucket LDS sort) ----
    hipMemsetAsync(bcounts, 0, NCB * sizeof(int), stream);
    hist_kernel <<<256, 256, 0, stream>>>(rows, bcounts);
    scan_kernel <<<1, 1024, 0, stream>>>(bcounts, boffs, bcursor, offs);
    scatter_tile<<<NTILES, 256, 0, stream>>>(rows, cols, vals, bcursor, epk);
    bucket_sort <<<NCB, 256, 0, stream>>>(boffs, epk, offs);

    // ---- 3 CSR SpMM layers with fused accumulation ----
    spmm_row<1><<<rgrid, 256, 0, stream>>>(ue, ie, offs, epk, ws0, out);
    spmm_row<2><<<rgrid, 256, 0, stream>>>(ws0, nullptr, offs, epk, outCL, out);
    spmm_row<3><<<rgrid, 256, 0, stream>>>(outCL, nullptr, offs, epk, nullptr, out);

    // ---- pass-through copies last (restores cl region + protos) ----
    {
        int total4 = NROW_ELEMS / 4 + 2 * (2048 * 64 / 4);
        int grid = (total4 + 255) / 256;
        copy_pass<<<grid, 256, 0, stream>>>(ue, ie, up, ip, out);
    }
}

// Round 6
// 550.327 us; speedup vs baseline: 9.9955x; 1.4767x over previous
//
#include <hip/hip_runtime.h>

#define USER_NUM 100000
#define ITEM_NUM 150000
#define NTOT     250000           // USER_NUM + ITEM_NUM
#define EMB      64
#define NNZ      5000000
#define NROW_ELEMS (NTOT * EMB)   // 16,000,000 floats = 64 MB
#define NCB      977              // ceil(NTOT/256) coarse buckets of 256 rows
#define TILE     8192             // edges per scatter block
#define NTILES   ((NNZ + TILE - 1) / TILE)     // 611
#define SCAP     6144             // per-coarse-bucket LDS cap (mean 5120, +14 sigma)
#define PROTO_ELEMS (2048 * 64)   // 131072 floats per prototype array

// ---------------- bf16 helpers (manual RNE pack, shift expand) ---------------
__device__ __forceinline__ unsigned bf1(float x) {
    unsigned u = __float_as_uint(x);
    return (u + 0x7FFFu + ((u >> 16) & 1u)) >> 16;          // RNE
}
__device__ __forceinline__ unsigned pkbf(float a, float b) {
    return bf1(a) | (bf1(b) << 16);
}
__device__ __forceinline__ float bflo(unsigned u) { return __uint_as_float(u << 16); }
__device__ __forceinline__ float bfhi(unsigned u) { return __uint_as_float(u & 0xFFFF0000u); }

// ============================ coarse histogram ===============================
__global__ __launch_bounds__(256) void hist_kernel(const int* __restrict__ rows,
                                                   int* __restrict__ counts) {
    __shared__ int sh[NCB];
    for (int i = threadIdx.x; i < NCB; i += 256) sh[i] = 0;
    __syncthreads();
    int stride = gridDim.x * blockDim.x;
    const int4* rows4 = (const int4*)rows;
    for (int i = blockIdx.x * blockDim.x + threadIdx.x; i < NNZ / 4; i += stride) {
        int4 r = rows4[i];
        atomicAdd(&sh[r.x >> 8], 1);
        atomicAdd(&sh[r.y >> 8], 1);
        atomicAdd(&sh[r.z >> 8], 1);
        atomicAdd(&sh[r.w >> 8], 1);
    }
    __syncthreads();
    for (int i = threadIdx.x; i < NCB; i += 256)
        if (sh[i]) atomicAdd(&counts[i], sh[i]);
}

// exclusive scan over NCB<=1024 counts -> boffs + bcursor; also offs[NTOT]=NNZ
__global__ void scan_kernel(const int* __restrict__ counts, int* __restrict__ boffs,
                            int* __restrict__ bcursor, int* __restrict__ offs) {
    __shared__ int sm[1024];
    int t = threadIdx.x;
    int c = (t < NCB) ? counts[t] : 0;
    sm[t] = c; __syncthreads();
    for (int off = 1; off < 1024; off <<= 1) {
        int v = (t >= off) ? sm[t - off] : 0;
        __syncthreads();
        sm[t] += v;
        __syncthreads();
    }
    if (t < NCB) { boffs[t] = sm[t] - c; bcursor[t] = sm[t] - c; }
    if (t == 1023) { boffs[NCB] = sm[1023]; offs[NTOT] = sm[1023]; }
}

// ================= tile scatter with in-block write combining ================
__global__ __launch_bounds__(256) void scatter_tile(
        const int* __restrict__ rows, const int* __restrict__ cols,
        const float* __restrict__ vals, int* __restrict__ bcursor,
        int2* __restrict__ epk) {
    __shared__ unsigned meta[TILE];   // cb<<22 | lr<<13 | rank   (32 KB)
    __shared__ int cnt[NCB];
    __shared__ int base[NCB];
    int t = threadIdx.x;
    int tb = blockIdx.x * TILE;
    int nmax = NNZ - tb; if (nmax > TILE) nmax = TILE;
    for (int i = t; i < NCB; i += 256) cnt[i] = 0;
    __syncthreads();
    for (int i = t; i < nmax; i += 256) {
        int r = rows[tb + i];
        int cb = r >> 8;
        int rank = atomicAdd(&cnt[cb], 1);
        meta[i] = ((unsigned)cb << 22) | ((unsigned)(r & 255) << 13) | (unsigned)rank;
    }
    __syncthreads();
    for (int i = t; i < NCB; i += 256) {
        int c = cnt[i];
        if (c) base[i] = atomicAdd(&bcursor[i], c);
    }
    __syncthreads();
    for (int i = t; i < nmax; i += 256) {
        unsigned m = meta[i];
        int cb = (int)(m >> 22);
        int lr = (int)((m >> 13) & 0x1FFu);
        int rank = (int)(m & 0x1FFFu);
        unsigned ex = (unsigned)cols[tb + i] | ((unsigned)lr << 18);
        epk[base[cb] + rank] = make_int2((int)ex, __float_as_int(vals[tb + i]));
    }
}

// ============== per-coarse-bucket in-LDS row sort + CSR offsets ==============
__global__ __launch_bounds__(256) void bucket_sort(const int* __restrict__ boffs,
                                                   int2* __restrict__ epk,
                                                   int* __restrict__ offs) {
    __shared__ int2 se[SCAP];         // 48 KB
    __shared__ int cnt[256];
    __shared__ int base[256];
    __shared__ int cur[256];
    int b = blockIdx.x, t = threadIdx.x;
    int beg = boffs[b], end = boffs[b + 1];
    int n = end - beg; if (n > SCAP) n = SCAP;   // +14 sigma, unreachable
    cnt[t] = 0;
    __syncthreads();
    for (int i = t; i < n; i += 256) {
        int2 e = epk[beg + i];
        se[i] = e;
        atomicAdd(&cnt[(((unsigned)e.x) >> 18) & 0xFFu], 1);
    }
    __syncthreads();
    int c = cnt[t];
    base[t] = c; __syncthreads();
    for (int off = 1; off < 256; off <<= 1) {     // Hillis-Steele inclusive
        int v = (t >= off) ? base[t - off] : 0;
        __syncthreads();
        base[t] += v;
        __syncthreads();
    }
    int mybase = beg + base[t] - c;               // exclusive + global base
    cur[t] = mybase;
    int r = b * 256 + t;
    if (r < NTOT) offs[r] = mybase;
    __syncthreads();
    for (int i = t; i < n; i += 256) {
        int2 e = se[i];
        int lr = (int)((((unsigned)e.x) >> 18) & 0xFFu);
        int p = atomicAdd(&cur[lr], 1);
        epk[p] = make_int2((int)(((unsigned)e.x) & 0x3FFFFu), e.y);
    }
}

// ===================== convert: ego f32 -> bf16 xb, + pass-throughs =========
// Also writes the user_cl/item_cl f32 copy and the prototype copies.
__global__ __launch_bounds__(256) void convert_kernel(
        const float* __restrict__ ue, const float* __restrict__ ie,
        const float* __restrict__ up, const float* __restrict__ ip,
        ushort* __restrict__ xb, float* __restrict__ out) {
    const int NG = NROW_ELEMS / 8;               // 2,000,000 8-elem groups
    int g = blockIdx.x * blockDim.x + threadIdx.x;
    if (g < NG) {
        int base = g * 8;
        const float* src = (base < USER_NUM * EMB) ? ue + base
                                                   : ie + (base - USER_NUM * EMB);
        float4 a = ((const float4*)src)[0];
        float4 b = ((const float4*)src)[1];
        float4* oc = (float4*)(out + NROW_ELEMS + base);
        oc[0] = a; oc[1] = b;
        uint4 w;
        w.x = pkbf(a.x, a.y); w.y = pkbf(a.z, a.w);
        w.z = pkbf(b.x, b.y); w.w = pkbf(b.z, b.w);
        ((uint4*)xb)[g] = w;
    } else {
        int pj = (g - NG) * 8;
        if (pj < PROTO_ELEMS) {
            float4 a = *(const float4*)(up + pj), b = *(const float4*)(up + pj + 4);
            float4* o = (float4*)(out + 2 * NROW_ELEMS + pj);
            o[0] = a; o[1] = b;
        } else if (pj < 2 * PROTO_ELEMS) {
            int q = pj - PROTO_ELEMS;
            float4 a = *(const float4*)(ip + q), b = *(const float4*)(ip + q + 4);
            float4* o = (float4*)(out + 2 * NROW_ELEMS + PROTO_ELEMS + q);
            o[0] = a; o[1] = b;
        }
    }
}

// ===================== bf16-gather CSR SpMM (no atomics) =====================
// 8 lanes per row; lane l owns dims [8l, 8l+8): one uint4 (8 bf16) per edge.
// LAYER 1,2: acc -> lb (bf16).  LAYER 3: out = (ego0 + l1 + l2 + acc) * 0.25.

__device__ __forceinline__ void acc8(float* acc, float v, uint4 u) {
    acc[0] += v * bflo(u.x); acc[1] += v * bfhi(u.x);
    acc[2] += v * bflo(u.y); acc[3] += v * bfhi(u.y);
    acc[4] += v * bflo(u.z); acc[5] += v * bfhi(u.z);
    acc[6] += v * bflo(u.w); acc[7] += v * bfhi(u.w);
}

template <int LAYER>
__global__ __launch_bounds__(256) void spmm_bf(
        const ushort* __restrict__ xb,       // gather source (bf16, NTOT*64)
        const int* __restrict__ offs, const int2* __restrict__ epk,
        ushort* __restrict__ lb,             // layer output (bf16), LAYER 1/2
        const float* __restrict__ ue, const float* __restrict__ ie,   // LAYER 3
        const ushort* __restrict__ l1b, const ushort* __restrict__ l2b,// LAYER 3
        float* __restrict__ out) {           // LAYER 3
    int t = blockIdx.x * blockDim.x + threadIdx.x;
    int r = t >> 3, l = t & 7;
    if (r >= NTOT) return;
    const uint4* src = (const uint4*)xb;     // 8 uint4 per row
    int beg = offs[r], end = offs[r + 1];
    float acc[8] = {0.f, 0.f, 0.f, 0.f, 0.f, 0.f, 0.f, 0.f};
    int j = beg;
    for (; j + 3 < end; j += 4) {
        int2 e0 = epk[j], e1 = epk[j + 1], e2 = epk[j + 2], e3 = epk[j + 3];
        uint4 u0 = src[e0.x * 8 + l];
        uint4 u1 = src[e1.x * 8 + l];
        uint4 u2 = src[e2.x * 8 + l];
        uint4 u3 = src[e3.x * 8 + l];
        acc8(acc, __int_as_float(e0.y), u0);
        acc8(acc, __int_as_float(e1.y), u1);
        acc8(acc, __int_as_float(e2.y), u2);
        acc8(acc, __int_as_float(e3.y), u3);
    }
    for (; j < end; ++j) {
        int2 e0 = epk[j];
        uint4 u0 = src[e0.x * 8 + l];
        acc8(acc, __int_as_float(e0.y), u0);
    }
    int idx = r * 8 + l;                     // uint4 index into bf16 row space
    if (LAYER == 1 || LAYER == 2) {
        uint4 w;
        w.x = pkbf(acc[0], acc[1]); w.y = pkbf(acc[2], acc[3]);
        w.z = pkbf(acc[4], acc[5]); w.w = pkbf(acc[6], acc[7]);
        ((uint4*)lb)[idx] = w;
    } else {
        int base = r * EMB + l * 8;          // float index
        const float* ep = (r < USER_NUM) ? ue + base
                                         : ie + (base - USER_NUM * EMB);
        float4 ea = ((const float4*)ep)[0];
        float4 eb = ((const float4*)ep)[1];
        uint4 u1 = ((const uint4*)l1b)[idx];
        uint4 u2 = ((const uint4*)l2b)[idx];
        float4 o0, o1;
        o0.x = (ea.x + bflo(u1.x) + bflo(u2.x) + acc[0]) * 0.25f;
        o0.y = (ea.y + bfhi(u1.x) + bfhi(u2.x) + acc[1]) * 0.25f;
        o0.z = (ea.z + bflo(u1.y) + bflo(u2.y) + acc[2]) * 0.25f;
        o0.w = (ea.w + bfhi(u1.y) + bfhi(u2.y) + acc[3]) * 0.25f;
        o1.x = (eb.x + bflo(u1.z) + bflo(u2.z) + acc[4]) * 0.25f;
        o1.y = (eb.y + bfhi(u1.z) + bfhi(u2.z) + acc[5]) * 0.25f;
        o1.z = (eb.z + bflo(u1.w) + bflo(u2.w) + acc[6]) * 0.25f;
        o1.w = (eb.w + bfhi(u1.w) + bfhi(u2.w) + acc[7]) * 0.25f;
        float4* op = (float4*)(out + base);
        op[0] = o0; op[1] = o1;
    }
}

// =============================================================================
extern "C" void kernel_launch(void* const* d_in, const int* in_sizes, int n_in,
                              void* d_out, int out_size, void* d_ws, size_t ws_size,
                              hipStream_t stream) {
    const float* ue   = (const float*)d_in[0];
    const float* ie   = (const float*)d_in[1];
    const float* up   = (const float*)d_in[2];
    const float* ip   = (const float*)d_in[3];
    const float* vals = (const float*)d_in[4];
    const int*   rows = (const int*)d_in[5];
    const int*   cols = (const int*)d_in[6];
    float* out = (float*)d_out;

    // ws layout (4-byte units):
    //   [0, 8M)         xb      : bf16 ego (32 MB); ALIASED as l2b after spmm1
    //   [8M, 16M)       l1b     : bf16 layer-1 (32 MB)
    //   [16M, 26M)      epk     : 5M int2 edges (40 MB)
    //   26,000,000      offs    : NTOT+1 row offsets
    //   26,250,112      boffs   : NCB+1
    //   26,252,000      bcursor : NCB
    //   26,253,000      bcounts : NCB
    ushort* xb     = (ushort*)d_ws;                  // also l2b (dead after spmm1)
    ushort* l1b    = (ushort*)((int*)d_ws + 8000000);
    int2*   epk    = (int2*)((int*)d_ws + 16000000);
    int*    offs   = (int*)d_ws + 26000000;
    int*    boffs  = (int*)d_ws + 26250112;
    int*    bcursor= (int*)d_ws + 26252000;
    int*    bcounts= (int*)d_ws + 26253000;
    ushort* l2b    = xb;

    const int sgrid = (NTOT * 8 + 255) / 256;        // 7813
    const int cgrid = (NROW_ELEMS / 8 + 2 * PROTO_ELEMS / 8 + 255) / 256;

    // ---- build row-sorted CSR (tile scatter + per-bucket LDS sort) ----
    hipMemsetAsync(bcounts, 0, NCB * sizeof(int), stream);
    hist_kernel <<<256, 256, 0, stream>>>(rows, bcounts);
    scan_kernel <<<1, 1024, 0, stream>>>(bcounts, boffs, bcursor, offs);
    scatter_tile<<<NTILES, 256, 0, stream>>>(rows, cols, vals, bcursor, epk);
    bucket_sort <<<NCB, 256, 0, stream>>>(boffs, epk, offs);

    // ---- convert ego to bf16 + all f32 pass-through copies ----
    convert_kernel<<<cgrid, 256, 0, stream>>>(ue, ie, up, ip, xb, out);

    // ---- 3 bf16-gather SpMM layers; f32 assembly in layer 3 ----
    spmm_bf<1><<<sgrid, 256, 0, stream>>>(xb,  offs, epk, l1b,
                                          nullptr, nullptr, nullptr, nullptr, nullptr);
    spmm_bf<2><<<sgrid, 256, 0, stream>>>(l1b, offs, epk, l2b,
                                          nullptr, nullptr, nullptr, nullptr, nullptr);
    spmm_bf<3><<<sgrid, 256, 0, stream>>>(l2b, offs, epk, nullptr,
                                          ue, ie, l1b, l2b, out);
}